// Round 5
// baseline (332.961 us; speedup 1.0000x reference)
//
#include <hip/hip_runtime.h>

#define DIM     128
#define NAGENT  100
#define NCITY   5000
#define NBATCH  64
#define NA_PAD  101
#define SUSP_CAP 16384
#define EPS     1e-3f

#define CT      128                      // cities per block (K3), 128 threads
#define CTILES  ((NCITY + CT - 1) / CT)  // 40
#define AHALF   50                       // agents per staging pass

// ---- workspace layout (bytes) — identical to passing round 2 ----
#define OFF_CNT 0
#define OFF_SUS 512
#define OFF_KP  66048        // fp64 kproj [B][NAGENT][DIM]  (6.55 MB)
#define OFF_G32 6619648      // fp32 G     [B][NAGENT][DIM]  (3.28 MB)

// ---------------------------------------------------------------------------
// K1: kproj64[b][a][e] = sum_d agent[b][a][d] * Wk[d][e]   (fp64)  [round-2]
// ---------------------------------------------------------------------------
__global__ __launch_bounds__(128) void proj_k_kernel(const float* __restrict__ agent,
                                                     const float* __restrict__ Wk,
                                                     double* __restrict__ kp64) {
    const int ba = blockIdx.x;
    const int e  = threadIdx.x;

    __shared__ float s_a[DIM];
    s_a[e] = agent[(size_t)ba * DIM + e];
    __syncthreads();

    double acc = 0.0;
    #pragma unroll 8
    for (int d = 0; d < DIM; ++d)
        acc += (double)s_a[d] * (double)Wk[d * DIM + e];
    kp64[(size_t)ba * DIM + e] = acc;
}

// ---------------------------------------------------------------------------
// K2: G[b][a][d] = (float) sum_e Wq[d][e] * kp64[b][a][e]   [round-2]
// ---------------------------------------------------------------------------
__global__ __launch_bounds__(256) void gmat_kernel(const float* __restrict__ Wq,
                                                   const double* __restrict__ kp64,
                                                   float* __restrict__ G32) {
    const int b      = blockIdx.x >> 3;
    const int dchunk = blockIdx.x & 7;
    const int tid    = threadIdx.x;

    __shared__ float s_kp[DIM][NA_PAD];   // [e][a]

    const double* kpb = kp64 + (size_t)b * NAGENT * DIM;
    for (int i = tid; i < NAGENT * DIM; i += 256) {
        int a = i >> 7;
        int e = i & 127;
        s_kp[e][a] = (float)kpb[i];
    }
    __syncthreads();

    const int d0 = dchunk * 16;
    for (int i = tid; i < 16 * NAGENT; i += 256) {
        int dl = i / NAGENT;
        int a  = i - dl * NAGENT;
        int d  = d0 + dl;
        const float* wq = Wq + d * DIM;
        double acc = 0.0;
        #pragma unroll 8
        for (int e = 0; e < DIM; ++e)
            acc += (double)wq[e] * (double)s_kp[e][a];
        G32[((size_t)b * NAGENT + a) * DIM + d] = (float)acc;
    }
}

// ---------------------------------------------------------------------------
// K3: thread-per-city fp32 scores + fused top-2 argmax (round-2 structure).
// 128 threads/block (VGPR cap 256 -> city row cv[32] stays resident, no
// spill), G staged in TWO 50-agent passes (25.6 KB LDS -> 6 blocks/CU).
// Summation order identical to round 2 (4 split accumulators over k).
// ---------------------------------------------------------------------------
__global__ __launch_bounds__(128)
void score_kernel(const float* __restrict__ city,
                  const float* __restrict__ G32,
                  int* __restrict__ out,
                  int* __restrict__ counter,
                  int* __restrict__ suspects) {
    const int b   = blockIdx.x / CTILES;
    const int ct  = blockIdx.x % CTILES;
    const int tid = threadIdx.x;
    int c = ct * CT + tid;
    const bool valid = (c < NCITY);
    if (!valid) c = NCITY - 1;            // clamp: keep barriers uniform

    __shared__ float s_g[AHALF * DIM];    // 25.6 KB

    // city row -> 32 float4 in VGPRs
    const int bc = b * NCITY + c;
    float4 cv[DIM / 4];
    {
        const float4* csrc = (const float4*)(city + (size_t)bc * DIM);
        #pragma unroll
        for (int j = 0; j < DIM / 4; ++j) cv[j] = csrc[j];
    }

    const float4* gsrc = (const float4*)(G32 + (size_t)b * NAGENT * DIM);
    float4* gdst = (float4*)s_g;

    float best1 = -1e30f, best2 = -1e30f;
    int   bidx  = 0;

    for (int p = 0; p < 2; ++p) {
        if (p) __syncthreads();           // protect previous pass's reads
        // stage G rows [p*50, p*50+50)  (coalesced float4)
        for (int i = tid; i < AHALF * DIM / 4; i += CT)
            gdst[i] = gsrc[p * (AHALF * DIM / 4) + i];
        __syncthreads();

        for (int a = 0; a < AHALF; ++a) {
            const float4* g4 = (const float4*)(s_g + a * DIM);
            float a0 = 0.f, a1 = 0.f, a2 = 0.f, a3 = 0.f;
            #pragma unroll
            for (int j = 0; j < DIM / 4; ++j) {
                float4 g = g4[j];         // LDS broadcast (same addr all lanes)
                a0 = fmaf(cv[j].x, g.x, a0);
                a1 = fmaf(cv[j].y, g.y, a1);
                a2 = fmaf(cv[j].z, g.z, a2);
                a3 = fmaf(cv[j].w, g.w, a3);
            }
            float sc = (a0 + a1) + (a2 + a3);
            int ag = p * AHALF + a;
            if (sc > best1)      { best2 = best1; best1 = sc; bidx = ag; }
            else if (sc > best2) { best2 = sc; }
        }
    }

    if (valid) {
        out[bc] = bidx;
        if (best1 - best2 < EPS) {
            int slot = atomicAdd(counter, 1);
            if (slot < SUSP_CAP) suspects[slot] = bc;
        }
    }
}

// ---------------------------------------------------------------------------
// K4: exact fp64 re-resolution of suspect rows   [round-2, validated]
// ---------------------------------------------------------------------------
__global__ __launch_bounds__(128) void recheck_kernel(const float* __restrict__ city,
                                                      const float* __restrict__ Wq,
                                                      const double* __restrict__ kp64,
                                                      const int* __restrict__ counter,
                                                      const int* __restrict__ suspects,
                                                      int* __restrict__ out) {
    int n = *counter;
    if (n > SUSP_CAP) n = SUSP_CAP;
    const int e = threadIdx.x;

    __shared__ float  s_c[DIM];
    __shared__ double s_q[DIM];
    __shared__ double s_best[DIM];
    __shared__ int    s_bidx[DIM];

    for (int s = blockIdx.x; s < n; s += gridDim.x) {
        const int bc = suspects[s];
        const int b  = bc / NCITY;

        s_c[e] = city[(size_t)bc * DIM + e];
        __syncthreads();

        double acc = 0.0;
        #pragma unroll 8
        for (int d = 0; d < DIM; ++d)
            acc += (double)s_c[d] * (double)Wq[d * DIM + e];
        s_q[e] = acc;
        __syncthreads();

        double best = -1.0e300;
        int    bidx = 0x7fffffff;
        if (e < NAGENT) {
            const double* kr = kp64 + ((size_t)b * NAGENT + e) * DIM;
            double sc = 0.0;
            #pragma unroll 8
            for (int d = 0; d < DIM; ++d)
                sc += s_q[d] * kr[d];
            best = sc; bidx = e;
        }
        s_best[e] = best; s_bidx[e] = bidx;
        __syncthreads();

        for (int off = 64; off > 0; off >>= 1) {
            if (e < off) {
                double ov = s_best[e + off];
                int    oi = s_bidx[e + off];
                if (ov > s_best[e] || (ov == s_best[e] && oi < s_bidx[e])) {
                    s_best[e] = ov; s_bidx[e] = oi;
                }
            }
            __syncthreads();
        }
        if (e == 0) out[bc] = s_bidx[0];
        __syncthreads();
    }
}

// ---------------------------------------------------------------------------
extern "C" void kernel_launch(void* const* d_in, const int* in_sizes, int n_in,
                              void* d_out, int out_size, void* d_ws, size_t ws_size,
                              hipStream_t stream) {
    const float* agent = (const float*)d_in[0];   // [B, NA, D]
    const float* city  = (const float*)d_in[1];   // [B, NC, D]
    const float* Wq    = (const float*)d_in[2];   // [D, D]
    const float* Wk    = (const float*)d_in[3];   // [D, D]
    int* out = (int*)d_out;                       // [B, NC]

    char*   ws       = (char*)d_ws;
    int*    counter  = (int*)(ws + OFF_CNT);
    int*    suspects = (int*)(ws + OFF_SUS);
    double* kp64     = (double*)(ws + OFF_KP);
    float*  G32      = (float*)(ws + OFF_G32);

    hipMemsetAsync(counter, 0, sizeof(int), stream);

    proj_k_kernel<<<NBATCH * NAGENT, DIM, 0, stream>>>(agent, Wk, kp64);
    gmat_kernel<<<NBATCH * 8, 256, 0, stream>>>(Wq, kp64, G32);
    score_kernel<<<NBATCH * CTILES, CT, 0, stream>>>(city, G32, out, counter, suspects);
    recheck_kernel<<<256, DIM, 0, stream>>>(city, Wq, kp64, counter, suspects, out);
}

// Round 6
// 226.170 us; speedup vs baseline: 1.4722x; 1.4722x over previous
//
#include <hip/hip_runtime.h>

#define DIM     128
#define NAGENT  100
#define NCITY   5000
#define NBATCH  64
#define NA_PAD  101
#define SUSP_CAP 16384
#define EPS     1e-3f

#define CB      128                       // cities per block (K3)
#define CTILES  ((NCITY + CB - 1) / CB)   // 40
#define AHALF   50                        // agents per staging pass
#define GROW    36                        // float4 per G row in LDS (4 chunks of 9: 8 data + 1 pad)

// ---- workspace layout (bytes) — identical to passing rounds 2/5 ----
#define OFF_CNT 0
#define OFF_SUS 512
#define OFF_KP  66048        // fp64 kproj [B][NAGENT][DIM]  (6.55 MB)
#define OFF_G32 6619648      // fp32 G     [B][NAGENT][DIM]  (3.28 MB)

// ---------------------------------------------------------------------------
// K1: kproj64[b][a][e] = sum_d agent[b][a][d] * Wk[d][e]   (fp64)  [validated]
// ---------------------------------------------------------------------------
__global__ __launch_bounds__(128) void proj_k_kernel(const float* __restrict__ agent,
                                                     const float* __restrict__ Wk,
                                                     double* __restrict__ kp64) {
    const int ba = blockIdx.x;
    const int e  = threadIdx.x;

    __shared__ float s_a[DIM];
    s_a[e] = agent[(size_t)ba * DIM + e];
    __syncthreads();

    double acc = 0.0;
    #pragma unroll 8
    for (int d = 0; d < DIM; ++d)
        acc += (double)s_a[d] * (double)Wk[d * DIM + e];
    kp64[(size_t)ba * DIM + e] = acc;
}

// ---------------------------------------------------------------------------
// K2: G[b][a][d] = (float) sum_e Wq[d][e] * kp64[b][a][e]   [validated]
// ---------------------------------------------------------------------------
__global__ __launch_bounds__(256) void gmat_kernel(const float* __restrict__ Wq,
                                                   const double* __restrict__ kp64,
                                                   float* __restrict__ G32) {
    const int b      = blockIdx.x >> 3;
    const int dchunk = blockIdx.x & 7;
    const int tid    = threadIdx.x;

    __shared__ float s_kp[DIM][NA_PAD];   // [e][a]

    const double* kpb = kp64 + (size_t)b * NAGENT * DIM;
    for (int i = tid; i < NAGENT * DIM; i += 256) {
        int a = i >> 7;
        int e = i & 127;
        s_kp[e][a] = (float)kpb[i];
    }
    __syncthreads();

    const int d0 = dchunk * 16;
    for (int i = tid; i < 16 * NAGENT; i += 256) {
        int dl = i / NAGENT;
        int a  = i - dl * NAGENT;
        int d  = d0 + dl;
        const float* wq = Wq + d * DIM;
        double acc = 0.0;
        #pragma unroll 8
        for (int e = 0; e < DIM; ++e)
            acc += (double)wq[e] * (double)s_kp[e][a];
        G32[((size_t)b * NAGENT + a) * DIM + d] = (float)acc;
    }
}

// ---------------------------------------------------------------------------
// K3: k-split-4 x 2-cities-per-thread fp32 scores + fused top-2 argmax.
// 256 threads (4 waves). Lane role: kgroup = tid&3 (32-float k-chunk),
// slot = tid>>2 (0..63). Thread holds its k-chunk of cities cbase+slot and
// cbase+64+slot in VGPRs (16 float4). Per agent: 8 conflict-free b128 G
// reads feed 64 FMAs; 4-lane shfl_xor butterfly completes each dot.
// G rows padded in LDS: chunk kgroup at float4 idx kgroup*9+j  -> the 4
// kgroups hit disjoint bank clusters (free 16-lane broadcasts).
// ---------------------------------------------------------------------------
__global__ __launch_bounds__(256)
void score_kernel(const float* __restrict__ city,
                  const float* __restrict__ G32,
                  int* __restrict__ out,
                  int* __restrict__ counter,
                  int* __restrict__ suspects) {
    const int b    = blockIdx.x / CTILES;
    const int tile = blockIdx.x % CTILES;
    const int cbase = tile * CB;
    const int tid  = threadIdx.x;
    const int kg   = tid & 3;
    const int slot = tid >> 2;

    __shared__ float4 s_g4[AHALF * GROW];   // 28.8 KB

    // ---- cities for this thread (clamped; validity checked at write) ----
    int cA = cbase + slot;
    int cB = cbase + 64 + slot;
    const bool vA = (cA < NCITY);
    const bool vB = (cB < NCITY);
    if (!vA) cA = NCITY - 1;
    if (!vB) cB = NCITY - 1;

    // per-thread k-chunk of each city row: 8 contiguous float4
    float4 cvA[8], cvB[8];
    {
        const float4* pa = (const float4*)(city + ((size_t)b * NCITY + cA) * DIM) + kg * 8;
        const float4* pb = (const float4*)(city + ((size_t)b * NCITY + cB) * DIM) + kg * 8;
        #pragma unroll
        for (int j = 0; j < 8; ++j) { cvA[j] = pa[j]; cvB[j] = pb[j]; }
    }

    const float4* gsrc = (const float4*)(G32 + (size_t)b * NAGENT * DIM);

    float best1A = -1e30f, best2A = -1e30f; int bidxA = 0;
    float best1B = -1e30f, best2B = -1e30f; int bidxB = 0;

    for (int p = 0; p < 2; ++p) {
        if (p) __syncthreads();           // previous pass's reads done
        // stage 50 G rows, swizzle-padded (coalesced global float4 reads)
        for (int i = tid; i < AHALF * 32; i += 256) {
            int a  = i >> 5;
            int jp = i & 31;
            s_g4[a * GROW + (jp >> 3) * 9 + (jp & 7)] = gsrc[p * (AHALF * 32) + i];
        }
        __syncthreads();

        #pragma unroll 2
        for (int a = 0; a < AHALF; ++a) {
            const float4* grow = &s_g4[a * GROW + kg * 9];
            float aA0 = 0.f, aA1 = 0.f, aB0 = 0.f, aB1 = 0.f;
            #pragma unroll
            for (int j = 0; j < 8; ++j) {
                float4 g = grow[j];       // 16-lane broadcast, kgroups on disjoint banks
                aA0 = fmaf(cvA[j].x, g.x, aA0);
                aA1 = fmaf(cvA[j].y, g.y, aA1);
                aA0 = fmaf(cvA[j].z, g.z, aA0);
                aA1 = fmaf(cvA[j].w, g.w, aA1);
                aB0 = fmaf(cvB[j].x, g.x, aB0);
                aB1 = fmaf(cvB[j].y, g.y, aB1);
                aB0 = fmaf(cvB[j].z, g.z, aB0);
                aB1 = fmaf(cvB[j].w, g.w, aB1);
            }
            float sA = aA0 + aA1;
            float sB = aB0 + aB1;
            // butterfly across the 4 kgroups (stays within the wave)
            sA += __shfl_xor(sA, 1); sA += __shfl_xor(sA, 2);
            sB += __shfl_xor(sB, 1); sB += __shfl_xor(sB, 2);

            const int ag = p * AHALF + a;   // ascending -> first-index tie-break
            if (sA > best1A)      { best2A = best1A; best1A = sA; bidxA = ag; }
            else if (sA > best2A) { best2A = sA; }
            if (sB > best1B)      { best2B = best1B; best1B = sB; bidxB = ag; }
            else if (sB > best2B) { best2B = sB; }
        }
    }

    // one writer per 4-lane group (all lanes hold identical results)
    if (kg == 0) {
        if (vA) {
            const int bc = b * NCITY + cbase + slot;
            out[bc] = bidxA;
            if (best1A - best2A < EPS) {
                int s = atomicAdd(counter, 1);
                if (s < SUSP_CAP) suspects[s] = bc;
            }
        }
        if (vB) {
            const int bc = b * NCITY + cbase + 64 + slot;
            out[bc] = bidxB;
            if (best1B - best2B < EPS) {
                int s = atomicAdd(counter, 1);
                if (s < SUSP_CAP) suspects[s] = bc;
            }
        }
    }
}

// ---------------------------------------------------------------------------
// K4: exact fp64 re-resolution of suspect rows   [validated]
// ---------------------------------------------------------------------------
__global__ __launch_bounds__(128) void recheck_kernel(const float* __restrict__ city,
                                                      const float* __restrict__ Wq,
                                                      const double* __restrict__ kp64,
                                                      const int* __restrict__ counter,
                                                      const int* __restrict__ suspects,
                                                      int* __restrict__ out) {
    int n = *counter;
    if (n > SUSP_CAP) n = SUSP_CAP;
    const int e = threadIdx.x;

    __shared__ float  s_c[DIM];
    __shared__ double s_q[DIM];
    __shared__ double s_best[DIM];
    __shared__ int    s_bidx[DIM];

    for (int s = blockIdx.x; s < n; s += gridDim.x) {
        const int bc = suspects[s];
        const int b  = bc / NCITY;

        s_c[e] = city[(size_t)bc * DIM + e];
        __syncthreads();

        double acc = 0.0;
        #pragma unroll 8
        for (int d = 0; d < DIM; ++d)
            acc += (double)s_c[d] * (double)Wq[d * DIM + e];
        s_q[e] = acc;
        __syncthreads();

        double best = -1.0e300;
        int    bidx = 0x7fffffff;
        if (e < NAGENT) {
            const double* kr = kp64 + ((size_t)b * NAGENT + e) * DIM;
            double sc = 0.0;
            #pragma unroll 8
            for (int d = 0; d < DIM; ++d)
                sc += s_q[d] * kr[d];
            best = sc; bidx = e;
        }
        s_best[e] = best; s_bidx[e] = bidx;
        __syncthreads();

        for (int off = 64; off > 0; off >>= 1) {
            if (e < off) {
                double ov = s_best[e + off];
                int    oi = s_bidx[e + off];
                if (ov > s_best[e] || (ov == s_best[e] && oi < s_bidx[e])) {
                    s_best[e] = ov; s_bidx[e] = oi;
                }
            }
            __syncthreads();
        }
        if (e == 0) out[bc] = s_bidx[0];
        __syncthreads();
    }
}

// ---------------------------------------------------------------------------
extern "C" void kernel_launch(void* const* d_in, const int* in_sizes, int n_in,
                              void* d_out, int out_size, void* d_ws, size_t ws_size,
                              hipStream_t stream) {
    const float* agent = (const float*)d_in[0];   // [B, NA, D]
    const float* city  = (const float*)d_in[1];   // [B, NC, D]
    const float* Wq    = (const float*)d_in[2];   // [D, D]
    const float* Wk    = (const float*)d_in[3];   // [D, D]
    int* out = (int*)d_out;                       // [B, NC]

    char*   ws       = (char*)d_ws;
    int*    counter  = (int*)(ws + OFF_CNT);
    int*    suspects = (int*)(ws + OFF_SUS);
    double* kp64     = (double*)(ws + OFF_KP);
    float*  G32      = (float*)(ws + OFF_G32);

    hipMemsetAsync(counter, 0, sizeof(int), stream);

    proj_k_kernel<<<NBATCH * NAGENT, DIM, 0, stream>>>(agent, Wk, kp64);
    gmat_kernel<<<NBATCH * 8, 256, 0, stream>>>(Wq, kp64, G32);
    score_kernel<<<NBATCH * CTILES, 256, 0, stream>>>(city, G32, out, counter, suspects);
    recheck_kernel<<<256, DIM, 0, stream>>>(city, Wq, kp64, counter, suspects, out);
}

// Round 7
// 154.405 us; speedup vs baseline: 2.1564x; 1.4648x over previous
//
#include <hip/hip_runtime.h>

#define DIM     128
#define NAGENT  100
#define NAP     112          // agents padded to 7x16 for MFMA n-tiles
#define NCITY   5000
#define NBATCH  64
#define NA_PAD  101
#define SUSP_CAP 16384
#define EPS     2e-3f

#define CPB     64                         // cities per block (K3): 4 waves x 16
#define CTILES  ((NCITY + CPB - 1) / CPB)  // 79

// ---- workspace layout (bytes), total 7,012,864 (< proven 9.9 MB) ----
#define OFF_CNT 0
#define OFF_SUS 512                        // 64 KB suspect list
#define OFF_KP  66048                      // fp32 k [64][100][128] = 3,276,800
#define OFF_GHI 3342848                    // bf16 Ghi [64][112][128] = 1,835,008
#define OFF_GLO 5177856                    // bf16 Glo [64][112][128] = 1,835,008

typedef __attribute__((ext_vector_type(8))) short short8;
typedef __attribute__((ext_vector_type(4))) float f32x4;

__device__ __forceinline__ unsigned short bf16_rne(float x) {
    unsigned u = __float_as_uint(x);
    u += 0x7FFFu + ((u >> 16) & 1u);
    return (unsigned short)(u >> 16);
}
__device__ __forceinline__ float bf16_tof(unsigned short h) {
    return __uint_as_float(((unsigned)h) << 16);
}

// ---------------------------------------------------------------------------
// K1: k32[b][a][e] = sum_d agent[b][a][d] * Wk[d][e]  (fp64 accum, fp32 store)
// [round-1-validated structure]
// ---------------------------------------------------------------------------
__global__ __launch_bounds__(128) void proj_k_kernel(const float* __restrict__ agent,
                                                     const float* __restrict__ Wk,
                                                     float* __restrict__ kp32) {
    const int ba = blockIdx.x;
    const int e  = threadIdx.x;

    __shared__ float s_a[DIM];
    s_a[e] = agent[(size_t)ba * DIM + e];
    __syncthreads();

    double acc = 0.0;
    #pragma unroll 8
    for (int d = 0; d < DIM; ++d)
        acc += (double)s_a[d] * (double)Wk[d * DIM + e];
    kp32[(size_t)ba * DIM + e] = (float)acc;
}

// ---------------------------------------------------------------------------
// K2: G[b][a][d] = sum_e Wq[d][e] * k32[b][a][e]  (fp64 accum), emitted as
// split bf16 (hi + lo), agent rows [100,112) zeroed.  [round-2 structure]
// ---------------------------------------------------------------------------
__global__ __launch_bounds__(256) void gmat_kernel(const float* __restrict__ Wq,
                                                   const float* __restrict__ kp32,
                                                   unsigned short* __restrict__ Ghi,
                                                   unsigned short* __restrict__ Glo) {
    const int b      = blockIdx.x >> 3;
    const int dchunk = blockIdx.x & 7;
    const int tid    = threadIdx.x;

    __shared__ float s_kp[DIM][NA_PAD];   // [e][a]

    const float* kpb = kp32 + (size_t)b * NAGENT * DIM;
    for (int i = tid; i < NAGENT * DIM; i += 256) {
        int a = i >> 7;
        int e = i & 127;
        s_kp[e][a] = kpb[i];
    }
    __syncthreads();

    const int d0 = dchunk * 16;
    for (int i = tid; i < 16 * NAP; i += 256) {   // 1792 = 7 * 256
        int dl = i / NAP;
        int a  = i - dl * NAP;
        int d  = d0 + dl;
        unsigned short hi = 0, lo = 0;
        if (a < NAGENT) {
            const float* wq = Wq + d * DIM;
            double acc = 0.0;
            #pragma unroll 8
            for (int e = 0; e < DIM; ++e)
                acc += (double)wq[e] * (double)s_kp[e][a];
            float g = (float)acc;
            hi = bf16_rne(g);
            lo = bf16_rne(g - bf16_tof(hi));
        }
        Ghi[((size_t)b * NAP + a) * DIM + d] = hi;
        Glo[((size_t)b * NAP + a) * DIM + d] = lo;
    }
}

// ---------------------------------------------------------------------------
// K3: MFMA split-bf16 GEMM + fused top-2 argmax.
// Block: 64 cities (4 waves x 16) x all 112 agents. Wave: 16x112 via 7
// n-tiles of mfma_f32_16x16x32_bf16; score = hi*hi + hi*lo + lo*hi (fp32 acc).
// A (city): lane reads rows directly from global (coalesced, read once),
// converts fp32 -> hi/lo bf16. B (G): LDS-staged, XOR-swizzled (a&7)<<4.
// D layout (m89-verified): col=lane&15 (agent), row=(lane>>4)*4+reg (city).
// Top-2 via 4-step shfl_xor butterfly over the 16 agent-columns; ties and
// gap<EPS go to exact fp64 recheck.
// ---------------------------------------------------------------------------
__global__ __launch_bounds__(256)
void score_mfma_kernel(const float* __restrict__ city,
                       const unsigned short* __restrict__ Ghi,
                       const unsigned short* __restrict__ Glo,
                       int* __restrict__ out,
                       int* __restrict__ counter,
                       int* __restrict__ suspects) {
    const int b    = blockIdx.x / CTILES;
    const int ct   = blockIdx.x % CTILES;
    const int tid  = threadIdx.x;
    const int wave = tid >> 6;
    const int lane = tid & 63;
    const int col  = lane & 15;   // A-row (city) for loads / B-col (agent)
    const int kgrp = lane >> 4;   // k-chunk group 0..3

    __shared__ float4 s_hi4[NAP * 16];   // 28672 B, bf16 G-hi tile (swizzled)
    __shared__ float4 s_lo4[NAP * 16];   // 28672 B
    unsigned char* s_hi = (unsigned char*)s_hi4;
    unsigned char* s_lo = (unsigned char*)s_lo4;

    // ---- stage G tiles with XOR swizzle ----
    {
        const float4* srcH = (const float4*)(Ghi + (size_t)b * NAP * DIM);
        const float4* srcL = (const float4*)(Glo + (size_t)b * NAP * DIM);
        for (int i = tid; i < NAP * 16; i += 256) {   // 1792 = 7 * 256
            int a = i >> 4, j = i & 15;
            int off = (a * 256 + j * 16) ^ ((a & 7) << 4);
            *(float4*)(s_hi + off) = srcH[i];
            *(float4*)(s_lo + off) = srcL[i];
        }
    }

    // ---- A fragments: city rows, fp32 -> split bf16 (in parallel w/ staging) ----
    const int c0 = ct * CPB + wave * 16;
    int crow = c0 + col; if (crow > NCITY - 1) crow = NCITY - 1;
    const float* crp = city + ((size_t)b * NCITY + crow) * DIM + kgrp * 8;

    short8 aHi[4], aLo[4];
    #pragma unroll
    for (int ks = 0; ks < 4; ++ks) {
        float4 p0 = *(const float4*)(crp + ks * 32);
        float4 p1 = *(const float4*)(crp + ks * 32 + 4);
        float f[8] = {p0.x, p0.y, p0.z, p0.w, p1.x, p1.y, p1.z, p1.w};
        short8 h, l;
        #pragma unroll
        for (int j = 0; j < 8; ++j) {
            unsigned short hb = bf16_rne(f[j]);
            h[j] = (short)hb;
            l[j] = (short)bf16_rne(f[j] - bf16_tof(hb));
        }
        aHi[ks] = h;
        aLo[ks] = l;
    }

    __syncthreads();

    // ---- GEMM: 7 n-tiles x 4 K-steps x 3 precision passes ----
    f32x4 acc[7];
    #pragma unroll
    for (int t = 0; t < 7; ++t) {
        f32x4 a4 = {0.f, 0.f, 0.f, 0.f};
        const int arow = t * 16 + col;
        const int sw   = (arow & 7) << 4;
        #pragma unroll
        for (int ks = 0; ks < 4; ++ks) {
            int off = (arow * 256 + (ks * 4 + kgrp) * 16) ^ sw;
            short8 bH = *(const short8*)(s_hi + off);
            short8 bL = *(const short8*)(s_lo + off);
            a4 = __builtin_amdgcn_mfma_f32_16x16x32_bf16(aHi[ks], bH, a4, 0, 0, 0);
            a4 = __builtin_amdgcn_mfma_f32_16x16x32_bf16(aHi[ks], bL, a4, 0, 0, 0);
            a4 = __builtin_amdgcn_mfma_f32_16x16x32_bf16(aLo[ks], bH, a4, 0, 0, 0);
        }
        acc[t] = a4;
    }

    // ---- fused top-2 argmax (per output row = city) ----
    #pragma unroll
    for (int r = 0; r < 4; ++r) {
        float b1 = -1e30f, b2 = -1e30f; int i1 = 0x7fffffff;
        #pragma unroll
        for (int t = 0; t < 7; ++t) {
            int a  = t * 16 + col;
            float v = (a < NAGENT) ? acc[t][r] : -1e30f;
            if (v > b1)      { b2 = b1; b1 = v; i1 = a; }
            else if (v > b2) { b2 = v; }
        }
        #pragma unroll
        for (int m = 1; m <= 8; m <<= 1) {
            float ob1 = __shfl_xor(b1, m);
            int   oi1 = __shfl_xor(i1, m);
            float ob2 = __shfl_xor(b2, m);
            if (ob1 > b1 || (ob1 == b1 && oi1 < i1)) {
                b2 = fmaxf(b1, ob2); b1 = ob1; i1 = oi1;
            } else {
                b2 = fmaxf(b2, ob1);
            }
        }
        if (col == 0) {
            int c = c0 + kgrp * 4 + r;        // D row = (lane>>4)*4 + reg
            if (c < NCITY) {
                int bc = b * NCITY + c;
                out[bc] = i1;
                if (b1 - b2 < EPS) {
                    int s = atomicAdd(counter, 1);
                    if (s < SUSP_CAP) suspects[s] = bc;
                }
            }
        }
    }
}

// ---------------------------------------------------------------------------
// K4: exact fp64 re-resolution, kp-free via score[a] = agent_a . (Wk @ (Wq^T c))
//   q[e] = sum_d c[d] Wq[d][e];  r[d] = sum_e Wk[d][e] q[e];
//   score[a] = sum_d agent[a][d] r[d]   (identical value to round-1 math)
// ---------------------------------------------------------------------------
__global__ __launch_bounds__(128) void recheck_kernel(const float* __restrict__ city,
                                                      const float* __restrict__ agent,
                                                      const float* __restrict__ Wq,
                                                      const float* __restrict__ Wk,
                                                      const int* __restrict__ counter,
                                                      const int* __restrict__ suspects,
                                                      int* __restrict__ out) {
    int n = *counter;
    if (n > SUSP_CAP) n = SUSP_CAP;
    const int e = threadIdx.x;

    __shared__ float  s_c[DIM];
    __shared__ double s_q[DIM];
    __shared__ double s_r[DIM];
    __shared__ double s_best[DIM];
    __shared__ int    s_bidx[DIM];

    for (int s = blockIdx.x; s < n; s += gridDim.x) {
        const int bc = suspects[s];
        const int b  = bc / NCITY;

        s_c[e] = city[(size_t)bc * DIM + e];
        __syncthreads();

        double q = 0.0;
        #pragma unroll 8
        for (int d = 0; d < DIM; ++d)
            q += (double)s_c[d] * (double)Wq[d * DIM + e];   // coalesced over e
        s_q[e] = q;
        __syncthreads();

        double r = 0.0;
        #pragma unroll 8
        for (int k = 0; k < DIM; ++k)
            r += (double)Wk[e * DIM + k] * s_q[k];           // e plays role of d
        s_r[e] = r;
        __syncthreads();

        double best = -1.0e300;
        int    bidx = 0x7fffffff;
        if (e < NAGENT) {
            const float* ar = agent + ((size_t)b * NAGENT + e) * DIM;
            double sc = 0.0;
            #pragma unroll 8
            for (int d = 0; d < DIM; ++d)
                sc += (double)ar[d] * s_r[d];
            best = sc; bidx = e;
        }
        s_best[e] = best; s_bidx[e] = bidx;
        __syncthreads();

        for (int off = 64; off > 0; off >>= 1) {
            if (e < off) {
                double ov = s_best[e + off];
                int    oi = s_bidx[e + off];
                if (ov > s_best[e] || (ov == s_best[e] && oi < s_bidx[e])) {
                    s_best[e] = ov; s_bidx[e] = oi;
                }
            }
            __syncthreads();
        }
        if (e == 0) out[bc] = s_bidx[0];
        __syncthreads();
    }
}

// ---------------------------------------------------------------------------
extern "C" void kernel_launch(void* const* d_in, const int* in_sizes, int n_in,
                              void* d_out, int out_size, void* d_ws, size_t ws_size,
                              hipStream_t stream) {
    const float* agent = (const float*)d_in[0];   // [B, NA, D]
    const float* city  = (const float*)d_in[1];   // [B, NC, D]
    const float* Wq    = (const float*)d_in[2];   // [D, D]
    const float* Wk    = (const float*)d_in[3];   // [D, D]
    int* out = (int*)d_out;                       // [B, NC]

    char*           ws       = (char*)d_ws;
    int*            counter  = (int*)(ws + OFF_CNT);
    int*            suspects = (int*)(ws + OFF_SUS);
    float*          kp32     = (float*)(ws + OFF_KP);
    unsigned short* Ghi      = (unsigned short*)(ws + OFF_GHI);
    unsigned short* Glo      = (unsigned short*)(ws + OFF_GLO);

    hipMemsetAsync(counter, 0, sizeof(int), stream);

    proj_k_kernel<<<NBATCH * NAGENT, DIM, 0, stream>>>(agent, Wk, kp32);
    gmat_kernel<<<NBATCH * 8, 256, 0, stream>>>(Wq, kp32, Ghi, Glo);
    score_mfma_kernel<<<NBATCH * CTILES, 256, 0, stream>>>(city, Ghi, Glo, out, counter, suspects);
    recheck_kernel<<<1024, DIM, 0, stream>>>(city, agent, Wq, Wk, counter, suspects, out);
}

// Round 8
// 111.069 us; speedup vs baseline: 2.9978x; 1.3902x over previous
//
#include <hip/hip_runtime.h>

#define DIM     128
#define NAGENT  100
#define NAP     112          // agents padded to 7x16 MFMA n-tiles
#define NCITY   5000
#define NBATCH  64
#define NA_PAD  101
#define SUSP_CAP 16384
#define EPS     2e-3f

#define CPB     128                        // cities per block (K3): 8 waves x 16
#define CTILES  ((NCITY + CPB - 1) / CPB)  // 40
#define FRAG_PB 14336                      // bf16 elems per batch per buffer (hi or lo)
#define CHUNKS  3584                       // 16-B chunks per batch (hi+lo)

// ---- workspace layout (bytes), total 7,012,864 ----
#define OFF_CNT 0
#define OFF_SUS 512                        // 64 KB suspect list
#define OFF_KP  66048                      // fp32 k [64][100][128] = 3,276,800
#define OFF_GF  3342848                    // bf16 Gfrag [64][ hi 14336 | lo 14336 ] = 3,670,016

typedef __attribute__((ext_vector_type(8))) short short8;
typedef __attribute__((ext_vector_type(4))) float f32x4;

__device__ __forceinline__ unsigned short bf16_rne(float x) {
    unsigned u = __float_as_uint(x);
    u += 0x7FFFu + ((u >> 16) & 1u);
    return (unsigned short)(u >> 16);
}
__device__ __forceinline__ float bf16_tof(unsigned short h) {
    return __uint_as_float(((unsigned)h) << 16);
}

// ---------------------------------------------------------------------------
// K1: k32[b][a][e] = sum_d agent[b][a][d] * Wk[d][e]  (fp64 accum, 4-way ILP)
// ---------------------------------------------------------------------------
__global__ __launch_bounds__(128) void proj_k_kernel(const float* __restrict__ agent,
                                                     const float* __restrict__ Wk,
                                                     float* __restrict__ kp32) {
    const int ba = blockIdx.x;
    const int e  = threadIdx.x;

    __shared__ float s_a[DIM];
    s_a[e] = agent[(size_t)ba * DIM + e];
    __syncthreads();

    double a0 = 0.0, a1 = 0.0, a2 = 0.0, a3 = 0.0;
    #pragma unroll 8
    for (int d = 0; d < DIM; d += 4) {
        a0 += (double)s_a[d + 0] * (double)Wk[(d + 0) * DIM + e];
        a1 += (double)s_a[d + 1] * (double)Wk[(d + 1) * DIM + e];
        a2 += (double)s_a[d + 2] * (double)Wk[(d + 2) * DIM + e];
        a3 += (double)s_a[d + 3] * (double)Wk[(d + 3) * DIM + e];
    }
    kp32[(size_t)ba * DIM + e] = (float)((a0 + a1) + (a2 + a3));
}

// ---------------------------------------------------------------------------
// K2: G[b][a][d] = sum_e Wq[d][e] * k32[b][a][e] (fp64 accum, 4-way ILP),
// emitted as split bf16 (hi RNE + lo RNE) in MFMA-FRAGMENT ORDER:
//   t=a>>4, col=a&15, ks=d>>5, kgrp=(d>>3)&3, j=d&7, lane=kgrp*16+col
//   fidx = ((t*4+ks)*64 + lane)*8 + j;  pad agents [100,112) = 0.
// ---------------------------------------------------------------------------
__global__ __launch_bounds__(256) void gmat_kernel(const float* __restrict__ Wq,
                                                   const float* __restrict__ kp32,
                                                   unsigned short* __restrict__ Gf) {
    const int b      = blockIdx.x >> 3;
    const int dchunk = blockIdx.x & 7;
    const int tid    = threadIdx.x;

    __shared__ float s_kp[DIM][NA_PAD];   // [e][a]

    const float* kpb = kp32 + (size_t)b * NAGENT * DIM;
    for (int i = tid; i < NAGENT * DIM; i += 256) {
        int a = i >> 7;
        int e = i & 127;
        s_kp[e][a] = kpb[i];
    }
    __syncthreads();

    unsigned short* GfB = Gf + (size_t)b * (2 * FRAG_PB);
    const int d0 = dchunk * 16;
    for (int i = tid; i < 16 * NAP; i += 256) {   // 1792
        int dl = i / NAP;
        int a  = i - dl * NAP;
        int d  = d0 + dl;
        unsigned short hi = 0, lo = 0;
        if (a < NAGENT) {
            const float* wq = Wq + d * DIM;
            double q0 = 0.0, q1 = 0.0, q2 = 0.0, q3 = 0.0;
            #pragma unroll 8
            for (int e = 0; e < DIM; e += 4) {
                q0 += (double)wq[e + 0] * (double)s_kp[e + 0][a];
                q1 += (double)wq[e + 1] * (double)s_kp[e + 1][a];
                q2 += (double)wq[e + 2] * (double)s_kp[e + 2][a];
                q3 += (double)wq[e + 3] * (double)s_kp[e + 3][a];
            }
            float g = (float)((q0 + q1) + (q2 + q3));
            hi = bf16_rne(g);
            lo = bf16_rne(g - bf16_tof(hi));
        }
        int t = a >> 4, col = a & 15;
        int ks = d >> 5, kgrp = (d >> 3) & 3, j = d & 7;
        int fidx = (((t * 4 + ks) * 64) + (kgrp * 16 + col)) * 8 + j;
        GfB[fidx] = hi;
        GfB[FRAG_PB + fidx] = lo;
    }
}

// ---------------------------------------------------------------------------
// K3: MFMA split-bf16 GEMM + fused top-2 argmax.
// 512 threads = 8 waves x 16 cities = 128 cities/block x 112 agents.
// B (G) staged via global_load_lds in fragment order -> lane-linear LDS reads
// (zero bank conflicts). A (city) direct from global, fp32 -> hi/lo bf16.
// score = hi*hi + hi*lo + lo*hi (fp32 acc), identical numerics to round 7.
// D layout: col=lane&15 (agent), row=(lane>>4)*4+reg (city).
// ---------------------------------------------------------------------------
__global__ __launch_bounds__(512)
void score_mfma_kernel(const float* __restrict__ city,
                       const unsigned short* __restrict__ Gf,
                       int* __restrict__ out,
                       int* __restrict__ counter,
                       int* __restrict__ suspects) {
    const int b    = blockIdx.x / CTILES;
    const int ct   = blockIdx.x % CTILES;
    const int tid  = threadIdx.x;
    const int wave = tid >> 6;
    const int lane = tid & 63;
    const int col  = lane & 15;
    const int kgrp = lane >> 4;

    __shared__ short8 s_frag[CHUNKS];     // 57344 B: [hi 1792 | lo 1792] chunks

    // ---- async stage G fragments (linear copy, wave-uniform LDS dest) ----
    {
        const char* gsrc = (const char*)(Gf + (size_t)b * (2 * FRAG_PB));
        #pragma unroll
        for (int it = 0; it < CHUNKS / 512; ++it) {   // 7
            int chunk = it * 512 + tid;
            __builtin_amdgcn_global_load_lds(
                (const __attribute__((address_space(1))) unsigned int*)(gsrc + (size_t)chunk * 16),
                (__attribute__((address_space(3))) unsigned int*)((char*)s_frag + (it * 512 + wave * 64) * 16),
                16, 0, 0);
        }
    }

    // ---- A fragments: city rows fp32 -> split bf16 (overlaps async stage) ----
    const int c0 = ct * CPB + wave * 16;
    int crow = c0 + col; if (crow > NCITY - 1) crow = NCITY - 1;
    const float* crp = city + ((size_t)b * NCITY + crow) * DIM + kgrp * 8;

    short8 aHi[4], aLo[4];
    #pragma unroll
    for (int ks = 0; ks < 4; ++ks) {
        float4 p0 = *(const float4*)(crp + ks * 32);
        float4 p1 = *(const float4*)(crp + ks * 32 + 4);
        float f[8] = {p0.x, p0.y, p0.z, p0.w, p1.x, p1.y, p1.z, p1.w};
        short8 h, l;
        #pragma unroll
        for (int j = 0; j < 8; ++j) {
            unsigned short hb = bf16_rne(f[j]);
            h[j] = (short)hb;
            l[j] = (short)bf16_rne(f[j] - bf16_tof(hb));
        }
        aHi[ks] = h;
        aLo[ks] = l;
    }

    __syncthreads();   // drains vmcnt(0): fragments resident

    // ---- GEMM: 7 n-tiles x 4 K-steps x 3 precision passes ----
    f32x4 acc[7];
    #pragma unroll
    for (int t = 0; t < 7; ++t) {
        f32x4 a4 = {0.f, 0.f, 0.f, 0.f};
        #pragma unroll
        for (int ks = 0; ks < 4; ++ks) {
            int fi = (t * 4 + ks) * 64 + lane;        // lane-linear: conflict-free
            short8 bH = s_frag[fi];
            short8 bL = s_frag[1792 + fi];
            a4 = __builtin_amdgcn_mfma_f32_16x16x32_bf16(aHi[ks], bH, a4, 0, 0, 0);
            a4 = __builtin_amdgcn_mfma_f32_16x16x32_bf16(aHi[ks], bL, a4, 0, 0, 0);
            a4 = __builtin_amdgcn_mfma_f32_16x16x32_bf16(aLo[ks], bH, a4, 0, 0, 0);
        }
        acc[t] = a4;
    }

    // ---- fused top-2 argmax (per output row = city) ----
    #pragma unroll
    for (int r = 0; r < 4; ++r) {
        float b1 = -1e30f, b2 = -1e30f; int i1 = 0x7fffffff;
        #pragma unroll
        for (int t = 0; t < 7; ++t) {
            int a  = t * 16 + col;
            float v = (a < NAGENT) ? acc[t][r] : -1e30f;
            if (v > b1)      { b2 = b1; b1 = v; i1 = a; }
            else if (v > b2) { b2 = v; }
        }
        #pragma unroll
        for (int m = 1; m <= 8; m <<= 1) {
            float ob1 = __shfl_xor(b1, m);
            int   oi1 = __shfl_xor(i1, m);
            float ob2 = __shfl_xor(b2, m);
            if (ob1 > b1 || (ob1 == b1 && oi1 < i1)) {
                b2 = fmaxf(b1, ob2); b1 = ob1; i1 = oi1;
            } else {
                b2 = fmaxf(b2, ob1);
            }
        }
        if (col == 0) {
            int c = c0 + kgrp * 4 + r;        // D row = (lane>>4)*4 + reg
            if (c < NCITY) {
                int bc = b * NCITY + c;
                out[bc] = i1;
                if (b1 - b2 < EPS) {
                    int s = atomicAdd(counter, 1);
                    if (s < SUSP_CAP) suspects[s] = bc;
                }
            }
        }
    }
}

// ---------------------------------------------------------------------------
// K4: exact fp64 re-resolution via score[a] = agent_a . (Wk @ (Wq^T c))
// [round-7-validated]
// ---------------------------------------------------------------------------
__global__ __launch_bounds__(128) void recheck_kernel(const float* __restrict__ city,
                                                      const float* __restrict__ agent,
                                                      const float* __restrict__ Wq,
                                                      const float* __restrict__ Wk,
                                                      const int* __restrict__ counter,
                                                      const int* __restrict__ suspects,
                                                      int* __restrict__ out) {
    int n = *counter;
    if (n > SUSP_CAP) n = SUSP_CAP;
    const int e = threadIdx.x;

    __shared__ float  s_c[DIM];
    __shared__ double s_q[DIM];
    __shared__ double s_r[DIM];
    __shared__ double s_best[DIM];
    __shared__ int    s_bidx[DIM];

    for (int s = blockIdx.x; s < n; s += gridDim.x) {
        const int bc = suspects[s];
        const int b  = bc / NCITY;

        s_c[e] = city[(size_t)bc * DIM + e];
        __syncthreads();

        double q = 0.0;
        #pragma unroll 8
        for (int d = 0; d < DIM; ++d)
            q += (double)s_c[d] * (double)Wq[d * DIM + e];
        s_q[e] = q;
        __syncthreads();

        double r = 0.0;
        #pragma unroll 8
        for (int k = 0; k < DIM; ++k)
            r += (double)Wk[e * DIM + k] * s_q[k];
        s_r[e] = r;
        __syncthreads();

        double best = -1.0e300;
        int    bidx = 0x7fffffff;
        if (e < NAGENT) {
            const float* ar = agent + ((size_t)b * NAGENT + e) * DIM;
            double sc = 0.0;
            #pragma unroll 8
            for (int d = 0; d < DIM; ++d)
                sc += (double)ar[d] * s_r[d];
            best = sc; bidx = e;
        }
        s_best[e] = best; s_bidx[e] = bidx;
        __syncthreads();

        for (int off = 64; off > 0; off >>= 1) {
            if (e < off) {
                double ov = s_best[e + off];
                int    oi = s_bidx[e + off];
                if (ov > s_best[e] || (ov == s_best[e] && oi < s_bidx[e])) {
                    s_best[e] = ov; s_bidx[e] = oi;
                }
            }
            __syncthreads();
        }
        if (e == 0) out[bc] = s_bidx[0];
        __syncthreads();
    }
}

// ---------------------------------------------------------------------------
extern "C" void kernel_launch(void* const* d_in, const int* in_sizes, int n_in,
                              void* d_out, int out_size, void* d_ws, size_t ws_size,
                              hipStream_t stream) {
    const float* agent = (const float*)d_in[0];   // [B, NA, D]
    const float* city  = (const float*)d_in[1];   // [B, NC, D]
    const float* Wq    = (const float*)d_in[2];   // [D, D]
    const float* Wk    = (const float*)d_in[3];   // [D, D]
    int* out = (int*)d_out;                       // [B, NC]

    char*           ws       = (char*)d_ws;
    int*            counter  = (int*)(ws + OFF_CNT);
    int*            suspects = (int*)(ws + OFF_SUS);
    float*          kp32     = (float*)(ws + OFF_KP);
    unsigned short* Gf       = (unsigned short*)(ws + OFF_GF);

    hipMemsetAsync(counter, 0, sizeof(int), stream);

    proj_k_kernel<<<NBATCH * NAGENT, DIM, 0, stream>>>(agent, Wk, kp32);
    gmat_kernel<<<NBATCH * 8, 256, 0, stream>>>(Wq, kp32, Gf);
    score_mfma_kernel<<<NBATCH * CTILES, 512, 0, stream>>>(city, Gf, out, counter, suspects);
    recheck_kernel<<<1024, DIM, 0, stream>>>(city, agent, Wq, Wk, counter, suspects, out);
}

// Round 9
// 106.423 us; speedup vs baseline: 3.1286x; 1.0437x over previous
//
#include <hip/hip_runtime.h>

#define DIM     128
#define NAGENT  100
#define NAP     112          // agents padded to 7x16 MFMA n-tiles
#define NCITY   5000
#define NBATCH  64
#define NA_PAD  101
#define SUSP_CAP 16384
#define EPS     2e-3f

#define CPB     128                        // cities per block (K3): 8 waves x 16
#define CTILES  ((NCITY + CPB - 1) / CPB)  // 40
#define FRAG_PB 14336                      // bf16 elems per batch per buffer (hi or lo)
#define CHUNKS  3584                       // 16-B chunks per batch (hi+lo)

// ---- workspace layout (bytes), total 7,012,864 ----
#define OFF_CNT 0
#define OFF_SUS 512                        // 64 KB suspect list
#define OFF_KP  66048                      // fp32 k [64][100][128] = 3,276,800
#define OFF_GF  3342848                    // bf16 Gfrag [64][ hi 14336 | lo 14336 ] = 3,670,016

typedef __attribute__((ext_vector_type(8))) short short8;
typedef __attribute__((ext_vector_type(4))) float f32x4;

__device__ __forceinline__ unsigned short bf16_rne(float x) {
    unsigned u = __float_as_uint(x);
    u += 0x7FFFu + ((u >> 16) & 1u);
    return (unsigned short)(u >> 16);
}
__device__ __forceinline__ float bf16_tof(unsigned short h) {
    return __uint_as_float(((unsigned)h) << 16);
}

// ---------------------------------------------------------------------------
// K1: k32[b][a][e] = sum_d agent[b][a][d] * Wk[d][e]  (fp64 accum, 4-way ILP)
// Also zeroes the suspect counter (replaces the 91-us hipMemsetAsync node;
// K1 -> K3 stream ordering makes this safe).
// ---------------------------------------------------------------------------
__global__ __launch_bounds__(128) void proj_k_kernel(const float* __restrict__ agent,
                                                     const float* __restrict__ Wk,
                                                     float* __restrict__ kp32,
                                                     int* __restrict__ counter) {
    const int ba = blockIdx.x;
    const int e  = threadIdx.x;

    if (ba == 0 && e == 0) *counter = 0;

    __shared__ float s_a[DIM];
    s_a[e] = agent[(size_t)ba * DIM + e];
    __syncthreads();

    double a0 = 0.0, a1 = 0.0, a2 = 0.0, a3 = 0.0;
    #pragma unroll 8
    for (int d = 0; d < DIM; d += 4) {
        a0 += (double)s_a[d + 0] * (double)Wk[(d + 0) * DIM + e];
        a1 += (double)s_a[d + 1] * (double)Wk[(d + 1) * DIM + e];
        a2 += (double)s_a[d + 2] * (double)Wk[(d + 2) * DIM + e];
        a3 += (double)s_a[d + 3] * (double)Wk[(d + 3) * DIM + e];
    }
    kp32[(size_t)ba * DIM + e] = (float)((a0 + a1) + (a2 + a3));
}

// ---------------------------------------------------------------------------
// K2: G[b][a][d] = sum_e Wq[d][e] * k32[b][a][e] (fp64 accum, 4-way ILP),
// emitted as split bf16 (hi RNE + lo RNE) in MFMA-FRAGMENT ORDER:
//   t=a>>4, col=a&15, ks=d>>5, kgrp=(d>>3)&3, j=d&7, lane=kgrp*16+col
//   fidx = ((t*4+ks)*64 + lane)*8 + j;  pad agents [100,112) = 0.
// ---------------------------------------------------------------------------
__global__ __launch_bounds__(256) void gmat_kernel(const float* __restrict__ Wq,
                                                   const float* __restrict__ kp32,
                                                   unsigned short* __restrict__ Gf) {
    const int b      = blockIdx.x >> 3;
    const int dchunk = blockIdx.x & 7;
    const int tid    = threadIdx.x;

    __shared__ float s_kp[DIM][NA_PAD];   // [e][a]

    const float* kpb = kp32 + (size_t)b * NAGENT * DIM;
    for (int i = tid; i < NAGENT * DIM; i += 256) {
        int a = i >> 7;
        int e = i & 127;
        s_kp[e][a] = kpb[i];
    }
    __syncthreads();

    unsigned short* GfB = Gf + (size_t)b * (2 * FRAG_PB);
    const int d0 = dchunk * 16;
    for (int i = tid; i < 16 * NAP; i += 256) {   // 1792
        int dl = i / NAP;
        int a  = i - dl * NAP;
        int d  = d0 + dl;
        unsigned short hi = 0, lo = 0;
        if (a < NAGENT) {
            const float* wq = Wq + d * DIM;
            double q0 = 0.0, q1 = 0.0, q2 = 0.0, q3 = 0.0;
            #pragma unroll 8
            for (int e = 0; e < DIM; e += 4) {
                q0 += (double)wq[e + 0] * (double)s_kp[e + 0][a];
                q1 += (double)wq[e + 1] * (double)s_kp[e + 1][a];
                q2 += (double)wq[e + 2] * (double)s_kp[e + 2][a];
                q3 += (double)wq[e + 3] * (double)s_kp[e + 3][a];
            }
            float g = (float)((q0 + q1) + (q2 + q3));
            hi = bf16_rne(g);
            lo = bf16_rne(g - bf16_tof(hi));
        }
        int t = a >> 4, col = a & 15;
        int ks = d >> 5, kgrp = (d >> 3) & 3, j = d & 7;
        int fidx = (((t * 4 + ks) * 64) + (kgrp * 16 + col)) * 8 + j;
        GfB[fidx] = hi;
        GfB[FRAG_PB + fidx] = lo;
    }
}

// ---------------------------------------------------------------------------
// K3: MFMA split-bf16 GEMM + fused top-2 argmax.
// 512 threads = 8 waves x 16 cities = 128 cities/block x 112 agents.
// B (G) staged via global_load_lds in fragment order -> lane-linear LDS reads
// (zero bank conflicts). A (city) direct from global, fp32 -> hi/lo bf16.
// score = hi*hi + hi*lo + lo*hi (fp32 acc).  [round-8-validated]
// D layout: col=lane&15 (agent), row=(lane>>4)*4+reg (city).
// ---------------------------------------------------------------------------
__global__ __launch_bounds__(512)
void score_mfma_kernel(const float* __restrict__ city,
                       const unsigned short* __restrict__ Gf,
                       int* __restrict__ out,
                       int* __restrict__ counter,
                       int* __restrict__ suspects) {
    const int b    = blockIdx.x / CTILES;
    const int ct   = blockIdx.x % CTILES;
    const int tid  = threadIdx.x;
    const int wave = tid >> 6;
    const int lane = tid & 63;
    const int col  = lane & 15;
    const int kgrp = lane >> 4;

    __shared__ short8 s_frag[CHUNKS];     // 57344 B: [hi 1792 | lo 1792] chunks

    // ---- async stage G fragments (linear copy, wave-uniform LDS dest) ----
    {
        const char* gsrc = (const char*)(Gf + (size_t)b * (2 * FRAG_PB));
        #pragma unroll
        for (int it = 0; it < CHUNKS / 512; ++it) {   // 7
            int chunk = it * 512 + tid;
            __builtin_amdgcn_global_load_lds(
                (const __attribute__((address_space(1))) unsigned int*)(gsrc + (size_t)chunk * 16),
                (__attribute__((address_space(3))) unsigned int*)((char*)s_frag + (it * 512 + wave * 64) * 16),
                16, 0, 0);
        }
    }

    // ---- A fragments: city rows fp32 -> split bf16 (overlaps async stage) ----
    const int c0 = ct * CPB + wave * 16;
    int crow = c0 + col; if (crow > NCITY - 1) crow = NCITY - 1;
    const float* crp = city + ((size_t)b * NCITY + crow) * DIM + kgrp * 8;

    short8 aHi[4], aLo[4];
    #pragma unroll
    for (int ks = 0; ks < 4; ++ks) {
        float4 p0 = *(const float4*)(crp + ks * 32);
        float4 p1 = *(const float4*)(crp + ks * 32 + 4);
        float f[8] = {p0.x, p0.y, p0.z, p0.w, p1.x, p1.y, p1.z, p1.w};
        short8 h, l;
        #pragma unroll
        for (int j = 0; j < 8; ++j) {
            unsigned short hb = bf16_rne(f[j]);
            h[j] = (short)hb;
            l[j] = (short)bf16_rne(f[j] - bf16_tof(hb));
        }
        aHi[ks] = h;
        aLo[ks] = l;
    }

    __syncthreads();   // drains vmcnt(0): fragments resident

    // ---- GEMM: 7 n-tiles x 4 K-steps x 3 precision passes ----
    f32x4 acc[7];
    #pragma unroll
    for (int t = 0; t < 7; ++t) {
        f32x4 a4 = {0.f, 0.f, 0.f, 0.f};
        #pragma unroll
        for (int ks = 0; ks < 4; ++ks) {
            int fi = (t * 4 + ks) * 64 + lane;        // lane-linear: conflict-free
            short8 bH = s_frag[fi];
            short8 bL = s_frag[1792 + fi];
            a4 = __builtin_amdgcn_mfma_f32_16x16x32_bf16(aHi[ks], bH, a4, 0, 0, 0);
            a4 = __builtin_amdgcn_mfma_f32_16x16x32_bf16(aHi[ks], bL, a4, 0, 0, 0);
            a4 = __builtin_amdgcn_mfma_f32_16x16x32_bf16(aLo[ks], bH, a4, 0, 0, 0);
        }
        acc[t] = a4;
    }

    // ---- fused top-2 argmax (per output row = city) ----
    #pragma unroll
    for (int r = 0; r < 4; ++r) {
        float b1 = -1e30f, b2 = -1e30f; int i1 = 0x7fffffff;
        #pragma unroll
        for (int t = 0; t < 7; ++t) {
            int a  = t * 16 + col;
            float v = (a < NAGENT) ? acc[t][r] : -1e30f;
            if (v > b1)      { b2 = b1; b1 = v; i1 = a; }
            else if (v > b2) { b2 = v; }
        }
        #pragma unroll
        for (int m = 1; m <= 8; m <<= 1) {
            float ob1 = __shfl_xor(b1, m);
            int   oi1 = __shfl_xor(i1, m);
            float ob2 = __shfl_xor(b2, m);
            if (ob1 > b1 || (ob1 == b1 && oi1 < i1)) {
                b2 = fmaxf(b1, ob2); b1 = ob1; i1 = oi1;
            } else {
                b2 = fmaxf(b2, ob1);
            }
        }
        if (col == 0) {
            int c = c0 + kgrp * 4 + r;        // D row = (lane>>4)*4 + reg
            if (c < NCITY) {
                int bc = b * NCITY + c;
                out[bc] = i1;
                if (b1 - b2 < EPS) {
                    int s = atomicAdd(counter, 1);
                    if (s < SUSP_CAP) suspects[s] = bc;
                }
            }
        }
    }
}

// ---------------------------------------------------------------------------
// K4: exact fp64 re-resolution via score[a] = agent_a . (Wk @ (Wq^T c))
// [round-7-validated]
// ---------------------------------------------------------------------------
__global__ __launch_bounds__(128) void recheck_kernel(const float* __restrict__ city,
                                                      const float* __restrict__ agent,
                                                      const float* __restrict__ Wq,
                                                      const float* __restrict__ Wk,
                                                      const int* __restrict__ counter,
                                                      const int* __restrict__ suspects,
                                                      int* __restrict__ out) {
    int n = *counter;
    if (n > SUSP_CAP) n = SUSP_CAP;
    const int e = threadIdx.x;

    __shared__ float  s_c[DIM];
    __shared__ double s_q[DIM];
    __shared__ double s_r[DIM];
    __shared__ double s_best[DIM];
    __shared__ int    s_bidx[DIM];

    for (int s = blockIdx.x; s < n; s += gridDim.x) {
        const int bc = suspects[s];
        const int b  = bc / NCITY;

        s_c[e] = city[(size_t)bc * DIM + e];
        __syncthreads();

        double q = 0.0;
        #pragma unroll 8
        for (int d = 0; d < DIM; ++d)
            q += (double)s_c[d] * (double)Wq[d * DIM + e];
        s_q[e] = q;
        __syncthreads();

        double r = 0.0;
        #pragma unroll 8
        for (int k = 0; k < DIM; ++k)
            r += (double)Wk[e * DIM + k] * s_q[k];
        s_r[e] = r;
        __syncthreads();

        double best = -1.0e300;
        int    bidx = 0x7fffffff;
        if (e < NAGENT) {
            const float* ar = agent + ((size_t)b * NAGENT + e) * DIM;
            double sc = 0.0;
            #pragma unroll 8
            for (int d = 0; d < DIM; ++d)
                sc += (double)ar[d] * s_r[d];
            best = sc; bidx = e;
        }
        s_best[e] = best; s_bidx[e] = bidx;
        __syncthreads();

        for (int off = 64; off > 0; off >>= 1) {
            if (e < off) {
                double ov = s_best[e + off];
                int    oi = s_bidx[e + off];
                if (ov > s_best[e] || (ov == s_best[e] && oi < s_bidx[e])) {
                    s_best[e] = ov; s_bidx[e] = oi;
                }
            }
            __syncthreads();
        }
        if (e == 0) out[bc] = s_bidx[0];
        __syncthreads();
    }
}

// ---------------------------------------------------------------------------
extern "C" void kernel_launch(void* const* d_in, const int* in_sizes, int n_in,
                              void* d_out, int out_size, void* d_ws, size_t ws_size,
                              hipStream_t stream) {
    const float* agent = (const float*)d_in[0];   // [B, NA, D]
    const float* city  = (const float*)d_in[1];   // [B, NC, D]
    const float* Wq    = (const float*)d_in[2];   // [D, D]
    const float* Wk    = (const float*)d_in[3];   // [D, D]
    int* out = (int*)d_out;                       // [B, NC]

    char*           ws       = (char*)d_ws;
    int*            counter  = (int*)(ws + OFF_CNT);
    int*            suspects = (int*)(ws + OFF_SUS);
    float*          kp32     = (float*)(ws + OFF_KP);
    unsigned short* Gf       = (unsigned short*)(ws + OFF_GF);

    proj_k_kernel<<<NBATCH * NAGENT, DIM, 0, stream>>>(agent, Wk, kp32, counter);
    gmat_kernel<<<NBATCH * 8, 256, 0, stream>>>(Wq, kp32, Gf);
    score_mfma_kernel<<<NBATCH * CTILES, 512, 0, stream>>>(city, Gf, out, counter, suspects);
    recheck_kernel<<<1024, DIM, 0, stream>>>(city, agent, Wq, Wk, counter, suspects, out);
}